// Round 12
// baseline (448.897 us; speedup 1.0000x reference)
//
#include <hip/hip_runtime.h>
#include <stdint.h>

// ---------------------------------------------------------------------------
// TopologicalContrastiveLoss: H0 persistence (MST edge weights) of 3 point
// clouds -> 1-Wasserstein between sorted death vectors -> hinge loss.
//
// R12 = R11 + symmetric GEMM: square 2D grid, blocks with bx<by exit
// immediately (528/1024 compute); mirror tile written through the existing
// 16KB smem as f16 (2 phases x 2 waves, 8KB/tile), 128B-contiguous mirror
// rows. R3's failure causes (triangular decode, fp32 TR occupancy hit,
// 4-phase serialization) individually addressed.
// ---------------------------------------------------------------------------

#define NPTS 4096
#define DIMF 1024
typedef unsigned short u16;
typedef _Float16 f16;
typedef unsigned long long ull;
static const ull KEY_MAX_ULL = ~0ull;

typedef f16 f16x8 __attribute__((ext_vector_type(8)));
typedef f16 f16x4v __attribute__((ext_vector_type(4)));
typedef float f32x4 __attribute__((ext_vector_type(4)));

#define GLOAD_LDS16(g, l)                                                      \
  __builtin_amdgcn_global_load_lds(                                            \
      (const __attribute__((address_space(1))) void*)(g),                      \
      (__attribute__((address_space(3))) void*)(l), 16, 0, 0)

// ------------------------------ init ---------------------------------------
__global__ void k_init_global(int* __restrict__ comp, ull* __restrict__ best,
                              float* __restrict__ deaths, int* __restrict__ cnt) {
  const int i = blockIdx.x * blockDim.x + threadIdx.x;
  if (i < 3 * NPTS) {
    comp[i] = i & (NPTS - 1);
    best[i] = KEY_MAX_ULL;
    deaths[i] = __int_as_float(0x7f800000);  // +inf
  }
  // cnt[0..2]=edge counters, cnt[3..5]=done, cnt[6..8]=C (start at NPTS)
  if (i < 16) cnt[i] = (i >= 6 && i < 9) ? NPTS : 0;
}

// ------------------------------ prep: norms + f16 cast ----------------------
__global__ __launch_bounds__(256)
void k_prep(const float* __restrict__ x, float* __restrict__ sq,
            f16* __restrict__ hi) {
  const int row = blockIdx.x;
  const int t = threadIdx.x;
  const float4 v = ((const float4*)(x + (size_t)row * DIMF))[t];
  f16x4v h;
  h.x = (f16)v.x; h.y = (f16)v.y; h.z = (f16)v.z; h.w = (f16)v.w;
  ((f16x4v*)(hi + (size_t)row * DIMF))[t] = h;
  float s = v.x * v.x + v.y * v.y + v.z * v.z + v.w * v.w;
  for (int off = 32; off > 0; off >>= 1) s += __shfl_xor(s, off, 64);
  __shared__ float ws[4];
  if ((t & 63) == 0) ws[t >> 6] = s;
  __syncthreads();
  if (t == 0) sq[row] = ws[0] + ws[1] + ws[2] + ws[3];
}

// -------------------- symmetric fp16 MFMA GEMM -> d16 -----------------------
// Upper-triangle tiles only (bx >= by); mirror via f16 LDS transpose.
__global__ __launch_bounds__(256)
void k_gemm_f16(const f16* __restrict__ hi, const float* __restrict__ sq,
                f16* __restrict__ d16) {
  if (blockIdx.x < blockIdx.y) return;  // lower-triangle blocks exit at once
  __shared__ u16 smem[8192];  // As 8KB + Bs 8KB; reused as TR (128x64 f16)
  u16* As = smem;
  u16* Bs = smem + 4096;
  const int t = threadIdx.x;
  const int w = t >> 6, l = t & 63;
  const int wm = w >> 1, wn = w & 1;
  const int ml = l & 15, kq = l >> 4;
  const int i0 = blockIdx.y * 128, j0 = blockIdx.x * 128;
  const bool diag = (blockIdx.x == blockIdx.y);

  const int srow = t >> 2, schk = t & 3;
  char* ldsA0 = (char*)As + t * 16;
  char* ldsB0 = (char*)Bs + t * 16;

  f32x4 acc[4][4];
#pragma unroll
  for (int a = 0; a < 4; ++a)
#pragma unroll
    for (int b = 0; b < 4; ++b) acc[a][b] = (f32x4)0.f;

  for (int k0 = 0; k0 < DIMF; k0 += 32) {
    __syncthreads();
    {
      const f16* ga0 = hi + (size_t)(i0 + srow) * DIMF + k0 + schk * 8;
      const f16* ga1 = hi + (size_t)(i0 + srow + 64) * DIMF + k0 + schk * 8;
      const f16* gb0 = hi + (size_t)(j0 + srow) * DIMF + k0 + schk * 8;
      const f16* gb1 = hi + (size_t)(j0 + srow + 64) * DIMF + k0 + schk * 8;
      GLOAD_LDS16(ga0, ldsA0);
      GLOAD_LDS16(ga1, ldsA0 + 4096);
      GLOAD_LDS16(gb0, ldsB0);
      GLOAD_LDS16(gb1, ldsB0 + 4096);
    }
    asm volatile("s_waitcnt vmcnt(0)" ::: "memory");
    __syncthreads();

    const char* Ab = (const char*)As + (wm * 64 + ml) * 64 + kq * 16;
    const char* Bb = (const char*)Bs + (wn * 64 + ml) * 64 + kq * 16;
    f16x8 af[4], bf[4];
#pragma unroll
    for (int mt = 0; mt < 4; ++mt) af[mt] = *(const f16x8*)(Ab + mt * 1024);
#pragma unroll
    for (int nt = 0; nt < 4; ++nt) bf[nt] = *(const f16x8*)(Bb + nt * 1024);
#pragma unroll
    for (int mt = 0; mt < 4; ++mt)
#pragma unroll
      for (int nt = 0; nt < 4; ++nt)
        acc[mt][nt] = __builtin_amdgcn_mfma_f32_16x16x32_f16(
            af[mt], bf[nt], acc[mt][nt], 0, 0, 0);
  }

  float sr[4][4], sc[4];
#pragma unroll
  for (int mt = 0; mt < 4; ++mt)
#pragma unroll
    for (int r = 0; r < 4; ++r)
      sr[mt][r] = sq[i0 + wm * 64 + mt * 16 + kq * 4 + r];
#pragma unroll
  for (int nt = 0; nt < 4; ++nt) sc[nt] = sq[j0 + wn * 64 + nt * 16 + ml];

  // direct stores (C/D layout: col=lane&15, row=(lane>>4)*4+reg)
#pragma unroll
  for (int mt = 0; mt < 4; ++mt)
#pragma unroll
    for (int nt = 0; nt < 4; ++nt) {
      const int col = j0 + wn * 64 + nt * 16 + ml;
#pragma unroll
      for (int r = 0; r < 4; ++r) {
        const int row = i0 + wm * 64 + mt * 16 + kq * 4 + r;
        const float v = fmaxf(sr[mt][r] + sc[nt] - 2.f * acc[mt][nt][r], 0.f);
        d16[(size_t)row * NPTS + col] = (f16)v;
      }
    }

  if (diag) return;

  // mirror: two phases; waves with wm==ph stage their 64x64 f16 tile into
  // TR[lcol(0..127)][lrow(0..63)], then all threads write 128 mirror rows.
  u16* TR = smem;  // 128*64 f16 = 16KB
  for (int ph = 0; ph < 2; ++ph) {
    __syncthreads();  // previous smem use done (K-loop reads / prior phase)
    if (wm == ph) {
#pragma unroll
      for (int mt = 0; mt < 4; ++mt)
#pragma unroll
        for (int nt = 0; nt < 4; ++nt) {
          const int lcol = wn * 64 + nt * 16 + ml;  // 0..127
#pragma unroll
          for (int r = 0; r < 4; ++r) {
            const int lrow = mt * 16 + kq * 4 + r;  // 0..63
            const float v =
                fmaxf(sr[mt][r] + sc[nt] - 2.f * acc[mt][nt][r], 0.f);
            TR[lcol * 64 + lrow] = (u16)__builtin_bit_cast(
                unsigned short, (f16)v);
          }
        }
    }
    __syncthreads();
    {
      const int rr = t >> 1;   // 0..127 mirror row offset
      const int hf = t & 1;    // 32-elem half
      const uint4* src = (const uint4*)(TR + rr * 64 + hf * 32);
      uint4* dst = (uint4*)(d16 + (size_t)(j0 + rr) * NPTS + i0 + ph * 64 +
                            hf * 32);
#pragma unroll
      for (int q = 0; q < 4; ++q) dst[q] = src[q];
    }
  }
}

// ------------- batched f16 Boruvka scan: 4 rows/block, gated ----------------
__global__ __launch_bounds__(256)
void k_scan3(const u16* __restrict__ d16, const int* __restrict__ comp,
             ull* __restrict__ best, const int* __restrict__ done,
             const int* __restrict__ Cdev) {
  const int b = blockIdx.x;          // 3 * 1024 blocks
  const int c = b >> 10;
  const int r0 = (b & 1023) * 4;
  if (done[c] || Cdev[c] <= 256) return;
  const int t = threadIdx.x;
  __shared__ ull red[4][4];
  const int* compc = comp + c * NPTS;
  int cj[16];
  {
    const int4* cp = (const int4*)compc;
    const int4 a0 = cp[t * 4 + 0], a1 = cp[t * 4 + 1];
    const int4 a2 = cp[t * 4 + 2], a3 = cp[t * 4 + 3];
    cj[0] = a0.x;  cj[1] = a0.y;  cj[2] = a0.z;  cj[3] = a0.w;
    cj[4] = a1.x;  cj[5] = a1.y;  cj[6] = a1.z;  cj[7] = a1.w;
    cj[8] = a2.x;  cj[9] = a2.y;  cj[10] = a2.z; cj[11] = a2.w;
    cj[12] = a3.x; cj[13] = a3.y; cj[14] = a3.z; cj[15] = a3.w;
  }
  int ci[4];
#pragma unroll
  for (int r = 0; r < 4; ++r) ci[r] = compc[r0 + r];
  const u16* base = d16 + (size_t)c * NPTS * NPTS;
  uint4 A[4], B[4];
#pragma unroll
  for (int r = 0; r < 4; ++r) {
    const uint4* rp = (const uint4*)(base + (size_t)(r0 + r) * NPTS);
    A[r] = rp[t * 2 + 0];
    B[r] = rp[t * 2 + 1];
  }
  ull km[4] = {KEY_MAX_ULL, KEY_MAX_ULL, KEY_MAX_ULL, KEY_MAX_ULL};
#pragma unroll
  for (int r = 0; r < 4; ++r) {
    const unsigned wds[8] = {A[r].x, A[r].y, A[r].z, A[r].w,
                             B[r].x, B[r].y, B[r].z, B[r].w};
    const int i = r0 + r;
    const int cir = ci[r];
#pragma unroll
    for (int u = 0; u < 8; ++u) {
      const int jc = t * 16 + u * 2;
      if (cj[u * 2] != cir) {
        const ull pair = (i < jc) ? (((ull)i << 12) | (unsigned)jc)
                                  : (((ull)jc << 12) | (unsigned)i);
        const ull key = ((ull)(wds[u] & 0xFFFFu) << 24) | pair;
        km[r] = (key < km[r]) ? key : km[r];
      }
      if (cj[u * 2 + 1] != cir) {
        const int j = jc + 1;
        const ull pair = (i < j) ? (((ull)i << 12) | (unsigned)j)
                                 : (((ull)j << 12) | (unsigned)i);
        const ull key = ((ull)(wds[u] >> 16) << 24) | pair;
        km[r] = (key < km[r]) ? key : km[r];
      }
    }
  }
  for (int off = 32; off > 0; off >>= 1) {
#pragma unroll
    for (int r = 0; r < 4; ++r) {
      const ull o = __shfl_xor(km[r], off, 64);
      km[r] = (o < km[r]) ? o : km[r];
    }
  }
  if ((t & 63) == 0) {
#pragma unroll
    for (int r = 0; r < 4; ++r) red[r][t >> 6] = km[r];
  }
  __syncthreads();
  if (t == 0) {
    ull m[4];
#pragma unroll
    for (int r = 0; r < 4; ++r) {
      m[r] = red[r][0];
#pragma unroll
      for (int q = 1; q < 4; ++q) m[r] = (red[r][q] < m[r]) ? red[r][q] : m[r];
    }
    ull* bestc = best + c * NPTS;
#pragma unroll
    for (int r = 0; r < 4; ++r) {
      if (m[r] == KEY_MAX_ULL) continue;
#pragma unroll
      for (int r2 = r + 1; r2 < 4; ++r2) {
        if (ci[r2] == ci[r]) {
          m[r] = (m[r2] < m[r]) ? m[r2] : m[r];
          m[r2] = KEY_MAX_ULL;
        }
      }
      atomicMin(bestc + ci[r], m[r]);
    }
  }
}

// -------------- batched merge (3 blocks; records PAIR indices) --------------
__global__ __launch_bounds__(1024)
void k_merge3(ull* __restrict__ best, int* __restrict__ comp,
              int* __restrict__ comp2, int* __restrict__ pairs,
              int* __restrict__ cnt, int* __restrict__ done,
              int* __restrict__ Cdev, ull* __restrict__ cd, int initCd) {
  const int c = blockIdx.x;
  if (done[c] || Cdev[c] <= 256) return;
  ull* bestc = best + c * NPTS;
  int* compc = comp + c * NPTS;
  int* comp2c = comp2 + c * NPTS;
  int* pairsc = pairs + c * NPTS;
  __shared__ int par[NPTS];
  __shared__ int hk[NPTS];
  __shared__ int redi[16];
  __shared__ int chg;
  __shared__ int cdense;
  const int t = threadIdx.x;
  ull bb[4];
#pragma unroll
  for (int s = 0; s < 4; ++s) {
    const int v = t + s * 1024;
    par[v] = compc[v];
    bb[s] = bestc[v];
    bestc[v] = KEY_MAX_ULL;
  }
  __syncthreads();
#pragma unroll
  for (int s = 0; s < 4; ++s) {
    const int v = t + s * 1024;
    const ull b2 = bb[s];
    int h;
    if (b2 == KEY_MAX_ULL) {
      h = par[v];
    } else {
      const int pair = (int)(b2 & 0xFFFFFF);
      const int a = pair >> 12, c2 = pair & 4095;
      const int ra = par[a], rb = par[c2];
      h = (ra == v) ? rb : ra;
    }
    hk[v] = h;
  }
  __syncthreads();
  bool win[4];
#pragma unroll
  for (int s = 0; s < 4; ++s) {
    const int v = t + s * 1024;
    const ull b2 = bb[s];
    win[s] = false;
    if (b2 != KEY_MAX_ULL) {
      const int so = hk[v];
      const bool mut = (hk[so] == v);
      win[s] = mut && (v < so);
      if (!mut || v < so)
        pairsc[atomicAdd(cnt + c, 1)] = (int)(b2 & 0xFFFFFF);
    }
  }
  if (t == 0) chg = 0;
  __syncthreads();
#pragma unroll
  for (int s = 0; s < 4; ++s)
    if (win[s]) hk[t + s * 1024] = t + s * 1024;
  __syncthreads();
  for (int it = 0; it < 12; ++it) {
    int w2[4]; int ch = 0;
#pragma unroll
    for (int s = 0; s < 4; ++s) {
      const int v = t + s * 1024;
      w2[s] = hk[hk[v]];
      ch |= (w2[s] != hk[v]);
    }
    __syncthreads();
#pragma unroll
    for (int s = 0; s < 4; ++s) hk[t + s * 1024] = w2[s];
    if (ch) chg = 1;
    __syncthreads();
    const int any = chg;
    __syncthreads();
    if (t == 0) chg = 0;
    if (!any) break;
  }
  int nroot = 0;
#pragma unroll
  for (int s = 0; s < 4; ++s) {
    const int v = t + s * 1024;
    const int rv = hk[v];
    compc[v] = rv;
    nroot += (rv == v);
  }
  for (int off = 32; off > 0; off >>= 1) nroot += __shfl_xor(nroot, off, 64);
  if ((t & 63) == 0) redi[t >> 6] = nroot;
  if (t == 0) cdense = 0;
  __syncthreads();
#pragma unroll
  for (int s = 0; s < 4; ++s) {
    const int v = t + s * 1024;
    if (hk[v] == v) par[v] = atomicAdd(&cdense, 1);
  }
  __syncthreads();
#pragma unroll
  for (int s = 0; s < 4; ++s) {
    const int v = t + s * 1024;
    comp2c[v] = par[hk[v]];
  }
  if (initCd) {  // round 0 (always runs): init this cloud's cd slice
    ull* cdc = cd + (size_t)c * 65536;
    for (int q = t; q < 65536; q += 1024) cdc[q] = KEY_MAX_ULL;
  }
  if (t == 0) {
    int tot = 0;
    for (int q = 0; q < 16; ++q) tot += redi[q];
    Cdev[c] = cdense;
    if (tot == 1) done[c] = 1;
  }
}

// ---------------------- batched contraction (f16 input) ---------------------
__global__ __launch_bounds__(256)
void k_contract3(const u16* __restrict__ d16, const int* __restrict__ comp2,
                 ull* __restrict__ cd, const int* __restrict__ done) {
  const int b = blockIdx.x;
  const int c = b >> 12;
  const int i = b & (NPTS - 1);
  if (done[c]) return;
  const int t = threadIdx.x;
  __shared__ ull tbl[256];
  tbl[t] = KEY_MAX_ULL;
  const int* comp2c = comp2 + c * NPTS;
  int cj[16];
  {
    const int4* cp = (const int4*)comp2c;
    const int4 a0 = cp[t * 4 + 0], a1 = cp[t * 4 + 1];
    const int4 a2 = cp[t * 4 + 2], a3 = cp[t * 4 + 3];
    cj[0] = a0.x;  cj[1] = a0.y;  cj[2] = a0.z;  cj[3] = a0.w;
    cj[4] = a1.x;  cj[5] = a1.y;  cj[6] = a1.z;  cj[7] = a1.w;
    cj[8] = a2.x;  cj[9] = a2.y;  cj[10] = a2.z; cj[11] = a2.w;
    cj[12] = a3.x; cj[13] = a3.y; cj[14] = a3.z; cj[15] = a3.w;
  }
  const int ci = comp2c[i];
  __syncthreads();
  const uint4* rp =
      (const uint4*)(d16 + (size_t)c * NPTS * NPTS + (size_t)i * NPTS);
  const uint4 Aw = rp[t * 2 + 0], Bw = rp[t * 2 + 1];
  const unsigned wds[8] = {Aw.x, Aw.y, Aw.z, Aw.w, Bw.x, Bw.y, Bw.z, Bw.w};
#pragma unroll
  for (int u = 0; u < 8; ++u) {
    const int j0c = t * 16 + u * 2;
    const unsigned lo = wds[u] & 0xFFFFu;
    const unsigned hi2 = wds[u] >> 16;
    const int c0 = cj[u * 2], c1 = cj[u * 2 + 1];
    if (c0 != ci) {
      const int j = j0c;
      const ull pair = (i < j) ? (((ull)i << 12) | (unsigned)j)
                               : (((ull)j << 12) | (unsigned)i);
      atomicMin(&tbl[c0], ((ull)lo << 24) | pair);
    }
    if (c1 != ci) {
      const int j = j0c + 1;
      const ull pair = (i < j) ? (((ull)i << 12) | (unsigned)j)
                               : (((ull)j << 12) | (unsigned)i);
      atomicMin(&tbl[c1], ((ull)hi2 << 24) | pair);
    }
  }
  __syncthreads();
  const ull tv = tbl[t];
  if (tv != KEY_MAX_ULL) atomicMin(&cd[(size_t)c * 65536 + ci * 256 + t], tv);
}

// ----- batched finish (3 single-WG blocks; per-row min, no cell atomics) ----
__global__ __launch_bounds__(1024)
void k_finish3(const ull* __restrict__ cd, const int* __restrict__ comp2,
               const int* __restrict__ Cdev, int* __restrict__ pairs,
               int* __restrict__ cnt, const int* __restrict__ done) {
  const int c = blockIdx.x;
  if (done[c]) return;
  const ull* cdc = cd + (size_t)c * 65536;
  const int* comp2c = comp2 + c * NPTS;
  int* pairsc = pairs + c * NPTS;
  __shared__ ull bst[256];
  __shared__ int lbl[256];
  __shared__ int hk2[256];
  __shared__ int mk[256];
  __shared__ int nr_sh;
  const int t = threadIdx.x;
  const int C = Cdev[c];
  const int row = t >> 2;  // 4 threads per row
  const int sub = t & 3;
  if (t < 256) lbl[t] = t;
  __syncthreads();
  for (int round = 0; round < 9; ++round) {
    if (t < 256) { bst[t] = KEY_MAX_ULL; mk[t] = 0; }
    if (t == 0) nr_sh = 0;
    __syncthreads();
    if (row < C) {
      const int lr = lbl[row];
      const ull* rp2 = cdc + row * 256;
      ull kmin = KEY_MAX_ULL;
#pragma unroll 8
      for (int k = 0; k < 64; ++k) {
        const int d = sub + 4 * k;
        if (d < C && lbl[d] != lr) {
          const ull key = rp2[d];
          kmin = (key < kmin) ? key : kmin;
        }
      }
      ull o = __shfl_xor(kmin, 1, 64);
      kmin = (o < kmin) ? o : kmin;
      o = __shfl_xor(kmin, 2, 64);
      kmin = (o < kmin) ? o : kmin;
      if (sub == 0 && kmin != KEY_MAX_ULL) atomicMin(&bst[lr], kmin);
    }
    __syncthreads();
    if (t < 256) {
      int h = t;
      const ull b = bst[t];
      if (t < C && b != KEY_MAX_ULL) {
        const int pair = (int)(b & 0xFFFFFF);
        const int a = pair >> 12, b2 = pair & 4095;
        const int sa = lbl[comp2c[a]], sb = lbl[comp2c[b2]];
        const int other = (sa == t) ? sb : sa;
        const ull bo = bst[other];
        const bool mut = (bo != KEY_MAX_ULL) && ((int)(bo & 0xFFFFFF) == pair);
        bool rec;
        if (mut) { h = (t < other) ? t : other; rec = (t < other); }
        else     { h = other;                   rec = true; }
        if (rec) pairsc[atomicAdd(cnt + c, 1)] = pair;
      }
      hk2[t] = h;
    }
    __syncthreads();
    for (int it = 0; it < 8; ++it) {
      int w2 = 0;
      if (t < 256) w2 = hk2[hk2[t]];
      __syncthreads();
      if (t < 256) hk2[t] = w2;
      __syncthreads();
    }
    if (t < 256) lbl[t] = hk2[lbl[t]];
    __syncthreads();
    if (t < C) mk[lbl[t]] = 1;
    __syncthreads();
    if (t < 256 && mk[t]) atomicAdd(&nr_sh, 1);
    __syncthreads();
    if (nr_sh <= 1) break;
    __syncthreads();
  }
}

// ------------------ exact deaths from pristine fp32 inputs ------------------
__global__ __launch_bounds__(256)
void k_deaths3(const float* __restrict__ x0, const float* __restrict__ x1,
               const float* __restrict__ x2, const float* __restrict__ sq,
               const int* __restrict__ pairs, float* __restrict__ deaths) {
  const int b = blockIdx.x;
  const int c = b >> 12;
  const int s = b & (NPTS - 1);
  if (s >= NPTS - 1) return;  // 4095 real edges per cloud
  const int t = threadIdx.x;
  const int pr = pairs[c * NPTS + s];
  const int a = pr >> 12, e = pr & 4095;
  const float* X = (c == 0) ? x0 : (c == 1) ? x1 : x2;
  const float4 va = ((const float4*)(X + (size_t)a * DIMF))[t];
  const float4 vb = ((const float4*)(X + (size_t)e * DIMF))[t];
  float d = va.x * vb.x + va.y * vb.y + va.z * vb.z + va.w * vb.w;
  for (int off = 32; off > 0; off >>= 1) d += __shfl_xor(d, off, 64);
  __shared__ float ws[4];
  if ((t & 63) == 0) ws[t >> 6] = d;
  __syncthreads();
  if (t == 0) {
    const float dot = ws[0] + ws[1] + ws[2] + ws[3];
    const float dd = sq[c * NPTS + a] + sq[c * NPTS + e] - 2.f * dot;
    deaths[c * NPTS + s] = sqrtf(fmaxf(dd, 1e-12f));
  }
}

// ------------------------------ sort (bitonic, 4096 in LDS) -----------------
__global__ __launch_bounds__(1024)
void k_sort(float* __restrict__ deaths) {
  __shared__ float s[NPTS];
  float* g = deaths + (size_t)blockIdx.x * NPTS;
  const int t = threadIdx.x;
#pragma unroll
  for (int q = 0; q < 4; ++q) s[t + q * 1024] = g[t + q * 1024];
  for (int k = 2; k <= NPTS; k <<= 1) {
    for (int j = k >> 1; j > 0; j >>= 1) {
      __syncthreads();
#pragma unroll
      for (int q = 0; q < 4; ++q) {
        const int i = t + q * 1024;
        const int ixj = i ^ j;
        if (ixj > i) {
          const float a = s[i], b = s[ixj];
          const bool up = ((i & k) == 0);
          if ((a > b) == up) { s[i] = b; s[ixj] = a; }
        }
      }
    }
  }
  __syncthreads();
#pragma unroll
  for (int q = 0; q < 4; ++q) g[t + q * 1024] = s[t + q * 1024];
}

// ------------------------------ final loss ----------------------------------
__global__ __launch_bounds__(1024)
void k_final(const float* __restrict__ deaths, float* __restrict__ out) {
  const float* a = deaths;
  const float* p = deaths + NPTS;
  const float* n = deaths + 2 * NPTS;
  const int t = threadIdx.x;
  float s1 = 0.f, s2 = 0.f;
  for (int i = t; i < NPTS - 1; i += 1024) {
    s1 += fabsf(a[i] - p[i]);
    s2 += fabsf(a[i] - n[i]);
  }
  for (int off = 32; off > 0; off >>= 1) {
    s1 += __shfl_xor(s1, off, 64);
    s2 += __shfl_xor(s2, off, 64);
  }
  __shared__ float r1[16], r2[16];
  if ((t & 63) == 0) { r1[t >> 6] = s1; r2[t >> 6] = s2; }
  __syncthreads();
  if (t == 0) {
    float t1 = 0.f, t2 = 0.f;
    for (int q = 0; q < 16; ++q) { t1 += r1[q]; t2 += r2[q]; }
    out[0] = fmaxf(t1 - t2 + 1.0f, 0.0f);
  }
}

// ---------------------- fp32 fallback path (small ws) -----------------------
__global__ __launch_bounds__(256)
void k_norms(const float* __restrict__ x, float* __restrict__ sq) {
  const int row = blockIdx.x;
  const int t = threadIdx.x;
  const float4 v = ((const float4*)(x + (size_t)row * DIMF))[t];
  float s = v.x * v.x + v.y * v.y + v.z * v.z + v.w * v.w;
  for (int off = 32; off > 0; off >>= 1) s += __shfl_xor(s, off, 64);
  __shared__ float ws[4];
  if ((t & 63) == 0) ws[t >> 6] = s;
  __syncthreads();
  if (t == 0) sq[row] = ws[0] + ws[1] + ws[2] + ws[3];
}

__global__ void k_init_cloud(int* __restrict__ comp, ull* __restrict__ best,
                             int* __restrict__ done) {
  int i = blockIdx.x * blockDim.x + threadIdx.x;
  if (i < NPTS) { comp[i] = i; best[i] = KEY_MAX_ULL; }
  if (i == 0) *done = 0;
}

__global__ void k_init_deaths(float* __restrict__ deaths, int* __restrict__ cnt) {
  int i = blockIdx.x * blockDim.x + threadIdx.x;
  if (i < 3 * NPTS) deaths[i] = __int_as_float(0x7f800000);
  if (i < 8) cnt[i] = 0;
}

#define BM 128
#define BN 128
#define BK 16
__global__ __launch_bounds__(256)
void k_gemm_d2(const float* __restrict__ X, const float* __restrict__ sq,
               float* __restrict__ d2) {
  __shared__ float As[BK][BM];
  __shared__ float Bs[BK][BN];
  const int tid = threadIdx.x;
  const int tx = tid & 15, ty = tid >> 4;
  const int i0 = blockIdx.y * BM, j0 = blockIdx.x * BN;
  float acc[8][8] = {};
  for (int k0 = 0; k0 < DIMF; k0 += BK) {
#pragma unroll
    for (int id = tid; id < 512; id += 256) {
      const int row = id >> 2;
      const int kk = (id & 3) << 2;
      const float4 a = *(const float4*)(X + (size_t)(i0 + row) * DIMF + k0 + kk);
      const float4 b = *(const float4*)(X + (size_t)(j0 + row) * DIMF + k0 + kk);
      As[kk + 0][row] = a.x; As[kk + 1][row] = a.y;
      As[kk + 2][row] = a.z; As[kk + 3][row] = a.w;
      Bs[kk + 0][row] = b.x; Bs[kk + 1][row] = b.y;
      Bs[kk + 2][row] = b.z; Bs[kk + 3][row] = b.w;
    }
    __syncthreads();
#pragma unroll
    for (int kk = 0; kk < BK; ++kk) {
      float a[8], b[8];
#pragma unroll
      for (int m = 0; m < 8; ++m) a[m] = As[kk][ty * 8 + m];
#pragma unroll
      for (int n = 0; n < 8; ++n) b[n] = Bs[kk][tx * 8 + n];
#pragma unroll
      for (int m = 0; m < 8; ++m)
#pragma unroll
        for (int n = 0; n < 8; ++n)
          acc[m][n] = fmaf(a[m], b[n], acc[m][n]);
    }
    __syncthreads();
  }
#pragma unroll
  for (int m = 0; m < 8; ++m) {
    const int i = i0 + ty * 8 + m;
    const float si = sq[i];
    const int j = j0 + tx * 8;
    float4 o0, o1;
    o0.x = fmaxf(si + sq[j + 0] - 2.f * acc[m][0], 0.f);
    o0.y = fmaxf(si + sq[j + 1] - 2.f * acc[m][1], 0.f);
    o0.z = fmaxf(si + sq[j + 2] - 2.f * acc[m][2], 0.f);
    o0.w = fmaxf(si + sq[j + 3] - 2.f * acc[m][3], 0.f);
    o1.x = fmaxf(si + sq[j + 4] - 2.f * acc[m][4], 0.f);
    o1.y = fmaxf(si + sq[j + 5] - 2.f * acc[m][5], 0.f);
    o1.z = fmaxf(si + sq[j + 6] - 2.f * acc[m][6], 0.f);
    o1.w = fmaxf(si + sq[j + 7] - 2.f * acc[m][7], 0.f);
    *(float4*)(d2 + (size_t)i * NPTS + j) = o0;
    *(float4*)(d2 + (size_t)i * NPTS + j + 4) = o1;
  }
}

__global__ __launch_bounds__(256)
void k_scan32(const float* __restrict__ d2, const int* __restrict__ comp,
              ull* __restrict__ best, const int* __restrict__ done) {
  if (*done) return;
  const int i = blockIdx.x;
  const int t = threadIdx.x;
  __shared__ ull red[4];
  int cj[16];
  {
    const int4* cp = (const int4*)comp;
    const int4 a0 = cp[t * 4 + 0], a1 = cp[t * 4 + 1];
    const int4 a2 = cp[t * 4 + 2], a3 = cp[t * 4 + 3];
    cj[0] = a0.x;  cj[1] = a0.y;  cj[2] = a0.z;  cj[3] = a0.w;
    cj[4] = a1.x;  cj[5] = a1.y;  cj[6] = a1.z;  cj[7] = a1.w;
    cj[8] = a2.x;  cj[9] = a2.y;  cj[10] = a2.z; cj[11] = a2.w;
    cj[12] = a3.x; cj[13] = a3.y; cj[14] = a3.z; cj[15] = a3.w;
  }
  const int ci = comp[i];
  const float* row = d2 + (size_t)i * NPTS;
  ull kmin = KEY_MAX_ULL;
#pragma unroll
  for (int q = 0; q < 4; ++q) {
    const float4 v = ((const float4*)row)[t * 4 + q];
    const float vv[4] = {v.x, v.y, v.z, v.w};
#pragma unroll
    for (int u = 0; u < 4; ++u) {
      const int j = t * 16 + q * 4 + u;
      if (cj[q * 4 + u] != ci) {
        const ull pair = (i < j) ? (((ull)i << 12) | (unsigned)j)
                                 : (((ull)j << 12) | (unsigned)i);
        const ull key = ((ull)__float_as_uint(vv[u]) << 24) | pair;
        kmin = (key < kmin) ? key : kmin;
      }
    }
  }
  for (int off = 32; off > 0; off >>= 1) {
    const ull o = __shfl_xor(kmin, off, 64);
    kmin = (o < kmin) ? o : kmin;
  }
  if ((t & 63) == 0) red[t >> 6] = kmin;
  __syncthreads();
  if (t == 0) {
    ull k2 = red[0];
    k2 = (red[1] < k2) ? red[1] : k2;
    k2 = (red[2] < k2) ? red[2] : k2;
    k2 = (red[3] < k2) ? red[3] : k2;
    if (k2 != KEY_MAX_ULL) atomicMin(best + ci, k2);
  }
}

__global__ __launch_bounds__(1024)
void k_merge1(ull* __restrict__ best, int* __restrict__ comp,
              const float* __restrict__ d2, float* __restrict__ deaths,
              int* __restrict__ cnt, int* __restrict__ done) {
  if (*done) return;
  __shared__ int par[NPTS];
  __shared__ int hk[NPTS];
  __shared__ int redi[16];
  const int t = threadIdx.x;
  ull bb[4];
#pragma unroll
  for (int s = 0; s < 4; ++s) {
    const int v = t + s * 1024;
    par[v] = comp[v];
    bb[s] = best[v];
    best[v] = KEY_MAX_ULL;
  }
  __syncthreads();
#pragma unroll
  for (int s = 0; s < 4; ++s) {
    const int v = t + s * 1024;
    const ull b2 = bb[s];
    int h;
    if (b2 == KEY_MAX_ULL) {
      h = par[v];
    } else {
      const int pair = (int)(b2 & 0xFFFFFF);
      const int a = pair >> 12, c2 = pair & 4095;
      const int ra = par[a], rb = par[c2];
      h = (ra == v) ? rb : ra;
    }
    hk[v] = h;
  }
  __syncthreads();
  bool win[4];
#pragma unroll
  for (int s = 0; s < 4; ++s) {
    const int v = t + s * 1024;
    const ull b2 = bb[s];
    win[s] = false;
    if (b2 != KEY_MAX_ULL) {
      const int so = hk[v];
      const bool mut = (hk[so] == v);
      win[s] = mut && (v < so);
      if (!mut || v < so) {
        const int pair = (int)(b2 & 0xFFFFFF);
        const float dd = d2[(size_t)(pair >> 12) * NPTS + (pair & 4095)];
        deaths[atomicAdd(cnt, 1)] = sqrtf(fmaxf(dd, 1e-12f));
      }
    }
  }
  __syncthreads();
#pragma unroll
  for (int s = 0; s < 4; ++s)
    if (win[s]) hk[t + s * 1024] = t + s * 1024;
  __syncthreads();
  for (int it = 0; it < 12; ++it) {
    int w2[4];
#pragma unroll
    for (int s = 0; s < 4; ++s) w2[s] = hk[hk[t + s * 1024]];
    __syncthreads();
#pragma unroll
    for (int s = 0; s < 4; ++s) hk[t + s * 1024] = w2[s];
    __syncthreads();
  }
  int nroot = 0;
#pragma unroll
  for (int s = 0; s < 4; ++s) {
    const int v = t + s * 1024;
    const int rv = hk[v];
    comp[v] = rv;
    nroot += (rv == v);
  }
  for (int off = 32; off > 0; off >>= 1) nroot += __shfl_xor(nroot, off, 64);
  if ((t & 63) == 0) redi[t >> 6] = nroot;
  __syncthreads();
  if (t == 0) {
    int tot = 0;
    for (int q = 0; q < 16; ++q) tot += redi[q];
    if (tot == 1) *done = 1;
  }
}

__global__ void k_fail(float* out) { if (threadIdx.x == 0) out[0] = 0.f; }

// ------------------------------ launch --------------------------------------
extern "C" void kernel_launch(void* const* d_in, const int* in_sizes, int n_in,
                              void* d_out, int out_size, void* d_ws, size_t ws_size,
                              hipStream_t stream) {
  const float* xs[3] = {(const float*)d_in[0], (const float*)d_in[1],
                        (const float*)d_in[2]};
  char* ws = (char*)d_ws;
  const size_t d16_one = (size_t)NPTS * NPTS * 2;      // 32MB
  const size_t d16_all = 3 * d16_one;                  // 96MB
  const size_t hi_bytes = (size_t)NPTS * DIMF * 2;     // 8MB (cd aliases this)
  const size_t tail_new = 3 * NPTS * 4 /*sq*/ + 3 * NPTS * 4 /*comp*/ +
                          3 * NPTS * 4 /*comp2*/ + 3 * NPTS * 8 /*best*/ +
                          3 * NPTS * 4 /*deaths*/ + 3 * NPTS * 4 /*pairs*/ + 128;
  const size_t need_new = d16_all + hi_bytes + tail_new;        // ~109.4MB
  const size_t d2_bytes = (size_t)NPTS * NPTS * 4;              // 64MB
  const size_t small_old = NPTS * 4 + NPTS * 4 + NPTS * 8 + 3 * NPTS * 4 + 128;
  const size_t need_old = d2_bytes + small_old;

  if (ws_size >= need_new) {
    f16* d16 = (f16*)ws;
    f16* hi = (f16*)(ws + d16_all);
    ull* cd = (ull*)(ws + d16_all);  // alias: hi dead after GEMMs
    char* tp = ws + d16_all + hi_bytes;
    float* sq = (float*)tp;                    tp += 3 * NPTS * 4;
    int* comp = (int*)tp;                      tp += 3 * NPTS * 4;
    int* comp2 = (int*)tp;                     tp += 3 * NPTS * 4;
    ull* best = (ull*)tp;                      tp += 3 * NPTS * 8;
    float* deaths = (float*)tp;                tp += 3 * NPTS * 4;
    int* pairs = (int*)tp;                     tp += 3 * NPTS * 4;
    int* cnt = (int*)tp;  // cnt[0..2], done = cnt+3, C = cnt+6
    int* done = cnt + 3;
    int* Cdev = cnt + 6;

    k_init_global<<<48, 256, 0, stream>>>(comp, best, deaths, cnt);
    for (int c = 0; c < 3; ++c) {
      k_prep<<<NPTS, 256, 0, stream>>>(xs[c], sq + c * NPTS, hi);
      k_gemm_f16<<<dim3(32, 32), 256, 0, stream>>>(
          hi, sq + c * NPTS, d16 + (size_t)c * NPTS * NPTS);
    }
    for (int r = 0; r < 4; ++r) {  // gated: rounds stop once C <= 256
      k_scan3<<<3 * (NPTS / 4), 256, 0, stream>>>((const u16*)d16, comp, best,
                                                  done, Cdev);
      k_merge3<<<3, 1024, 0, stream>>>(best, comp, comp2, pairs, cnt, done,
                                       Cdev, cd, (r == 0) ? 1 : 0);
    }
    k_contract3<<<3 * NPTS, 256, 0, stream>>>((const u16*)d16, comp2, cd, done);
    k_finish3<<<3, 1024, 0, stream>>>(cd, comp2, Cdev, pairs, cnt, done);
    k_deaths3<<<3 * NPTS, 256, 0, stream>>>(xs[0], xs[1], xs[2], sq, pairs,
                                            deaths);
    k_sort<<<3, 1024, 0, stream>>>(deaths);
    k_final<<<1, 1024, 0, stream>>>(deaths, (float*)d_out);
  } else if (ws_size >= need_old) {
    float* d2 = (float*)ws;
    char* tp = ws + d2_bytes;
    float* sq = (float*)tp;                    tp += NPTS * 4;
    int* comp = (int*)tp;                      tp += NPTS * 4;
    ull* best = (ull*)tp;                      tp += NPTS * 8;
    float* deaths = (float*)tp;                tp += 3 * NPTS * 4;
    int* cnt = (int*)tp;
    int* done = cnt + 3;
    k_init_deaths<<<48, 256, 0, stream>>>(deaths, cnt);
    for (int c = 0; c < 3; ++c) {
      k_norms<<<NPTS, 256, 0, stream>>>(xs[c], sq);
      k_init_cloud<<<16, 256, 0, stream>>>(comp, best, done);
      k_gemm_d2<<<dim3(NPTS / BN, NPTS / BM), 256, 0, stream>>>(xs[c], sq, d2);
      for (int r = 0; r < 12; ++r) {
        k_scan32<<<NPTS, 256, 0, stream>>>(d2, comp, best, done);
        k_merge1<<<1, 1024, 0, stream>>>(best, comp, d2, deaths + c * NPTS,
                                         cnt + c, done);
      }
    }
    k_sort<<<3, 1024, 0, stream>>>(deaths);
    k_final<<<1, 1024, 0, stream>>>(deaths, (float*)d_out);
  } else {
    k_fail<<<1, 64, 0, stream>>>((float*)d_out);
  }
}